// Round 8
// baseline (462.141 us; speedup 1.0000x reference)
//
#include <hip/hip_runtime.h>

#define NB 64      // batch (sequences)
#define NH 32      // q heads
#define NKV 8      // kv heads
#define HD 128     // head dim
#define NG 4       // q heads per kv head
#define PAGE 32
#define PPS 64     // pages per seq
#define SMAX 2048
#define CHUNK 128  // tokens per split-S block
#define CPP (CHUNK / PAGE)   // 4 pages per chunk
#define NCH (SMAX / CHUNK)   // 16
#define SCALE 0.08838834764831843f

// cross-lane add via DPP (VALU pipe, no LDS). CTRL: 0xB1=quad_perm xor1,
// 0x4E=quad_perm xor2, 0x124=row_ror:4, 0x128=row_ror:8.
template <int CTRL>
__device__ __forceinline__ float dpp_xadd(float v) {
    int t = __builtin_amdgcn_update_dpp(0, __float_as_int(v), CTRL, 0xF, 0xF, false);
    return v + __int_as_float(t);
}

// sum-reduce + broadcast across a 32-lane half-wave: 4 DPP adds + 1 ds_swizzle(xor16)
__device__ __forceinline__ float rsum32(float x) {
    x = dpp_xadd<0xB1>(x);
    x = dpp_xadd<0x4E>(x);
    x = dpp_xadd<0x124>(x);
    x = dpp_xadd<0x128>(x);
    int y = __builtin_amdgcn_ds_swizzle(__float_as_int(x), 0x401F);  // xor 16
    return x + __int_as_float(y);
}

// online-softmax update; defer-rescale (exact: skipping when no new max means e=1)
__device__ __forceinline__ void oupd(
    float d0, float d1, float d2, float d3, const float4 vv,
    float& m0, float& m1, float& m2, float& m3,
    float& l0, float& l1, float& l2, float& l3,
    float4& a0, float4& a1, float4& a2, float4& a3)
{
    if (d0 > m0 || d1 > m1 || d2 > m2 || d3 > m3) {
        const float n0 = fmaxf(m0, d0), n1 = fmaxf(m1, d1);
        const float n2 = fmaxf(m2, d2), n3 = fmaxf(m3, d3);
        const float e0 = __expf(m0 - n0), e1 = __expf(m1 - n1);
        const float e2 = __expf(m2 - n2), e3 = __expf(m3 - n3);
        const float p0 = __expf(d0 - n0), p1 = __expf(d1 - n1);
        const float p2 = __expf(d2 - n2), p3 = __expf(d3 - n3);
        m0 = n0; m1 = n1; m2 = n2; m3 = n3;
        l0 = l0 * e0 + p0; l1 = l1 * e1 + p1;
        l2 = l2 * e2 + p2; l3 = l3 * e3 + p3;
        a0.x = a0.x * e0 + p0 * vv.x; a0.y = a0.y * e0 + p0 * vv.y;
        a0.z = a0.z * e0 + p0 * vv.z; a0.w = a0.w * e0 + p0 * vv.w;
        a1.x = a1.x * e1 + p1 * vv.x; a1.y = a1.y * e1 + p1 * vv.y;
        a1.z = a1.z * e1 + p1 * vv.z; a1.w = a1.w * e1 + p1 * vv.w;
        a2.x = a2.x * e2 + p2 * vv.x; a2.y = a2.y * e2 + p2 * vv.y;
        a2.z = a2.z * e2 + p2 * vv.z; a2.w = a2.w * e2 + p2 * vv.w;
        a3.x = a3.x * e3 + p3 * vv.x; a3.y = a3.y * e3 + p3 * vv.y;
        a3.z = a3.z * e3 + p3 * vv.z; a3.w = a3.w * e3 + p3 * vv.w;
    } else {
        const float p0 = __expf(d0 - m0), p1 = __expf(d1 - m1);
        const float p2 = __expf(d2 - m2), p3 = __expf(d3 - m3);
        l0 += p0; l1 += p1; l2 += p2; l3 += p3;
        a0.x += p0 * vv.x; a0.y += p0 * vv.y; a0.z += p0 * vv.z; a0.w += p0 * vv.w;
        a1.x += p1 * vv.x; a1.y += p1 * vv.y; a1.z += p1 * vv.z; a1.w += p1 * vv.w;
        a2.x += p2 * vv.x; a2.y += p2 * vv.y; a2.z += p2 * vv.z; a2.w += p2 * vv.w;
        a3.x += p3 * vv.x; a3.y += p3 * vv.y; a3.z += p3 * vv.z; a3.w += p3 * vv.w;
    }
}

// ---------------- split-S partial kernel ----------------
// 128 threads (2 waves) per block -> 16 blocks/CU resident (wave cap 32),
// grid (NKV, NB, NCH=16): ~4350 active blocks vs 4096 resident slots ->
// near-total co-residency, no scheduling quantization rounds.
__global__ __launch_bounds__(128, 8) void paged_attn_split(
    const float* __restrict__ q,
    const float* __restrict__ knew,
    const float* __restrict__ vnew,
    const float* __restrict__ kcache,
    const float* __restrict__ vcache,
    const int*  __restrict__ btab,
    const int*  __restrict__ ctxlen,
    const int*  __restrict__ slotmap,
    float* __restrict__ pacc,   // [B*NKV*NCH*NG][HD]
    float* __restrict__ pml)    // [B*NKV*NCH*NG][2]
{
    const int kh  = blockIdx.x;
    const int b   = blockIdx.y;
    const int c   = blockIdx.z;
    const int tid = threadIdx.x;   // 0..127

    const int S  = ctxlen[b];
    const int c0 = c * CHUNK;
    if (c0 >= S) return;
    const int send = min(S, c0 + CHUNK);

    __shared__ int   bt_s[CPP];
    __shared__ int   ovr_s[CHUNK];        // -1 or max seq index j (last-write-wins)
    __shared__ float acc_s[4][NG][HD];    // per-half-wave partials (8 KB)
    __shared__ float ml_s[4][NG][2];

    if (tid < CPP) bt_s[tid] = btab[b * PPS + c * CPP + tid];
    ovr_s[tid] = -1;
    __syncthreads();
    if (tid < NB) {
        const int slot = slotmap[tid];
        const int pg = slot >> 5, pos = slot & 31;
        #pragma unroll
        for (int i = 0; i < CPP; ++i)
            if (bt_s[i] == pg) atomicMax(&ovr_s[i * PAGE + pos], tid);
    }
    __syncthreads();

    const int hw = tid >> 5;   // half-wave 0..3
    const int ln = tid & 31;   // lane; owns d = 4*ln..4*ln+3

    const float* qb = q + ((size_t)(b * NH + kh * NG)) * HD + 4 * ln;
    const float4 q0 = *(const float4*)(qb + 0 * HD);
    const float4 q1 = *(const float4*)(qb + 1 * HD);
    const float4 q2 = *(const float4*)(qb + 2 * HD);
    const float4 q3 = *(const float4*)(qb + 3 * HD);

    float m0 = -INFINITY, m1 = -INFINITY, m2 = -INFINITY, m3 = -INFINITY;
    float l0 = 0.f, l1 = 0.f, l2 = 0.f, l3 = 0.f;
    float4 a0 = {0,0,0,0}, a1 = {0,0,0,0}, a2 = {0,0,0,0}, a3 = {0,0,0,0};

    auto addr = [&](int sg, const float*& kp, const float*& vp) {
        const int r  = sg - c0;
        const int ov = ovr_s[r];
        if (ov >= 0) {
            const size_t o = ((size_t)ov * NKV + kh) * HD + 4 * ln;
            kp = knew + o; vp = vnew + o;
        } else {
            const size_t o = (((size_t)bt_s[r >> 5] * PAGE + (r & 31)) * NKV + kh) * HD + 4 * ln;
            kp = kcache + o; vp = vcache + o;
        }
    };

    int s = c0 + hw;
    for (; s + 4 < send; s += 8) {           // 2-token unroll: s and s+4
        const float *kpA, *vpA, *kpB, *vpB;
        addr(s,     kpA, vpA);
        addr(s + 4, kpB, vpB);
        const float4 kA = *(const float4*)kpA;
        const float4 kB = *(const float4*)kpB;
        const float4 vA = *(const float4*)vpA;
        const float4 vB = *(const float4*)vpB;

        float dA0 = q0.x*kA.x + q0.y*kA.y + q0.z*kA.z + q0.w*kA.w;
        float dA1 = q1.x*kA.x + q1.y*kA.y + q1.z*kA.z + q1.w*kA.w;
        float dA2 = q2.x*kA.x + q2.y*kA.y + q2.z*kA.z + q2.w*kA.w;
        float dA3 = q3.x*kA.x + q3.y*kA.y + q3.z*kA.z + q3.w*kA.w;
        float dB0 = q0.x*kB.x + q0.y*kB.y + q0.z*kB.z + q0.w*kB.w;
        float dB1 = q1.x*kB.x + q1.y*kB.y + q1.z*kB.z + q1.w*kB.w;
        float dB2 = q2.x*kB.x + q2.y*kB.y + q2.z*kB.z + q2.w*kB.w;
        float dB3 = q3.x*kB.x + q3.y*kB.y + q3.z*kB.z + q3.w*kB.w;

        dA0 = rsum32(dA0) * SCALE; dA1 = rsum32(dA1) * SCALE;
        dA2 = rsum32(dA2) * SCALE; dA3 = rsum32(dA3) * SCALE;
        dB0 = rsum32(dB0) * SCALE; dB1 = rsum32(dB1) * SCALE;
        dB2 = rsum32(dB2) * SCALE; dB3 = rsum32(dB3) * SCALE;

        oupd(dA0, dA1, dA2, dA3, vA, m0,m1,m2,m3, l0,l1,l2,l3, a0,a1,a2,a3);
        oupd(dB0, dB1, dB2, dB3, vB, m0,m1,m2,m3, l0,l1,l2,l3, a0,a1,a2,a3);
    }
    if (s < send) {
        const float *kp, *vp;
        addr(s, kp, vp);
        const float4 kv = *(const float4*)kp;
        const float4 vv = *(const float4*)vp;
        float d0 = q0.x*kv.x + q0.y*kv.y + q0.z*kv.z + q0.w*kv.w;
        float d1 = q1.x*kv.x + q1.y*kv.y + q1.z*kv.z + q1.w*kv.w;
        float d2 = q2.x*kv.x + q2.y*kv.y + q2.z*kv.z + q2.w*kv.w;
        float d3 = q3.x*kv.x + q3.y*kv.y + q3.z*kv.z + q3.w*kv.w;
        d0 = rsum32(d0) * SCALE; d1 = rsum32(d1) * SCALE;
        d2 = rsum32(d2) * SCALE; d3 = rsum32(d3) * SCALE;
        oupd(d0, d1, d2, d3, vv, m0,m1,m2,m3, l0,l1,l2,l3, a0,a1,a2,a3);
    }

    *(float4*)&acc_s[hw][0][4 * ln] = a0;
    *(float4*)&acc_s[hw][1][4 * ln] = a1;
    *(float4*)&acc_s[hw][2][4 * ln] = a2;
    *(float4*)&acc_s[hw][3][4 * ln] = a3;
    if (ln == 0) {
        ml_s[hw][0][0] = m0; ml_s[hw][0][1] = l0;
        ml_s[hw][1][0] = m1; ml_s[hw][1][1] = l1;
        ml_s[hw][2][0] = m2; ml_s[hw][2][1] = l2;
        ml_s[hw][3][0] = m3; ml_s[hw][3][1] = l3;
    }
    __syncthreads();

    for (int o = tid; o < NG * HD; o += 128) {
        const int h = o >> 7;
        const int d = o & 127;
        float M = -INFINITY;
        #pragma unroll
        for (int w = 0; w < 4; ++w) M = fmaxf(M, ml_s[w][h][0]);
        float L = 0.f, val = 0.f;
        #pragma unroll
        for (int w = 0; w < 4; ++w) {
            const float mm = ml_s[w][h][0];
            const float sc = (mm == -INFINITY) ? 0.f : __expf(mm - M);
            L   += sc * ml_s[w][h][1];
            val += sc * acc_s[w][h][d];
        }
        const size_t idx = ((size_t)((b * NKV + kh) * NCH + c) * NG + h);
        pacc[idx * HD + d] = val;
        if (d == 0) { pml[idx * 2] = M; pml[idx * 2 + 1] = L; }
    }
}

// ---------------- combine kernel ----------------
__global__ __launch_bounds__(256) void paged_attn_combine(
    const int*  __restrict__ ctxlen,
    const float* __restrict__ pacc,
    const float* __restrict__ pml,
    float* __restrict__ out)
{
    const int kh  = blockIdx.x;
    const int b   = blockIdx.y;
    const int tid = threadIdx.x;
    const int S   = ctxlen[b];
    const int nch = (S + CHUNK - 1) / CHUNK;

    __shared__ float ml_s[NCH][NG][2];
    if (tid < nch * NG) {
        const int cc = tid / NG, h = tid % NG;
        const size_t idx = ((size_t)((b * NKV + kh) * NCH + cc) * NG + h);
        ml_s[cc][h][0] = pml[idx * 2];
        ml_s[cc][h][1] = pml[idx * 2 + 1];
    }
    __syncthreads();

    for (int o = tid; o < NG * HD; o += 256) {
        const int h = o >> 7;
        const int d = o & 127;
        float M = -INFINITY;
        for (int cc = 0; cc < nch; ++cc) M = fmaxf(M, ml_s[cc][h][0]);
        float L = 0.f, val = 0.f;
        for (int cc = 0; cc < nch; ++cc) {
            const float sc = __expf(ml_s[cc][h][0] - M);
            L   += sc * ml_s[cc][h][1];
            val += sc * pacc[((size_t)((b * NKV + kh) * NCH + cc) * NG + h) * HD + d];
        }
        out[((size_t)(b * NH + kh * NG + h)) * HD + d] = val / L;
    }
}

// ---------------- monolithic fallback (only if ws too small) ----------------
__global__ __launch_bounds__(256) void paged_attn_mono(
    const float* __restrict__ q, const float* __restrict__ knew,
    const float* __restrict__ vnew, const float* __restrict__ kcache,
    const float* __restrict__ vcache, const int* __restrict__ btab,
    const int* __restrict__ ctxlen, const int* __restrict__ slotmap,
    float* __restrict__ out)
{
    const int kh  = blockIdx.x;
    const int b   = blockIdx.y;
    const int tid = threadIdx.x;

    __shared__ int   bt_s[PPS];
    __shared__ int   slot_s[NB];
    __shared__ short ovr_s[SMAX];
    __shared__ float acc_s[8][NG][HD];
    __shared__ float ml_s[8][NG][2];

    if (tid < PPS)              bt_s[tid]        = btab[b * PPS + tid];
    if (tid >= 64 && tid < 128) slot_s[tid - 64] = slotmap[tid - 64];
    for (int i = tid; i < SMAX; i += 256) ovr_s[i] = -1;
    __syncthreads();
    if (tid < PPS) {
        const int page = bt_s[tid];
        for (int j = 0; j < NB; ++j) {
            const int slot = slot_s[j];
            if ((slot >> 5) == page) ovr_s[tid * PAGE + (slot & 31)] = (short)j;
        }
    }
    __syncthreads();

    const int S  = ctxlen[b];
    const int hw = tid >> 5;
    const int ln = tid & 31;

    const float* qb = q + ((size_t)(b * NH + kh * NG)) * HD + 4 * ln;
    const float4 q0 = *(const float4*)(qb + 0 * HD);
    const float4 q1 = *(const float4*)(qb + 1 * HD);
    const float4 q2 = *(const float4*)(qb + 2 * HD);
    const float4 q3 = *(const float4*)(qb + 3 * HD);

    float m0 = -INFINITY, m1 = -INFINITY, m2 = -INFINITY, m3 = -INFINITY;
    float l0 = 0.f, l1 = 0.f, l2 = 0.f, l3 = 0.f;
    float4 a0 = {0,0,0,0}, a1 = {0,0,0,0}, a2 = {0,0,0,0}, a3 = {0,0,0,0};

    for (int s = hw; s < S; s += 8) {
        const int ov = ovr_s[s];
        const float* kp; const float* vp;
        if (ov >= 0) {
            const size_t o = ((size_t)ov * NKV + kh) * HD + 4 * ln;
            kp = knew + o; vp = vnew + o;
        } else {
            const size_t o = (((size_t)bt_s[s >> 5] * PAGE + (s & 31)) * NKV + kh) * HD + 4 * ln;
            kp = kcache + o; vp = vcache + o;
        }
        const float4 kv = *(const float4*)kp;
        const float4 vv = *(const float4*)vp;
        float d0 = q0.x*kv.x + q0.y*kv.y + q0.z*kv.z + q0.w*kv.w;
        float d1 = q1.x*kv.x + q1.y*kv.y + q1.z*kv.z + q1.w*kv.w;
        float d2 = q2.x*kv.x + q2.y*kv.y + q2.z*kv.z + q2.w*kv.w;
        float d3 = q3.x*kv.x + q3.y*kv.y + q3.z*kv.z + q3.w*kv.w;
        d0 = rsum32(d0) * SCALE; d1 = rsum32(d1) * SCALE;
        d2 = rsum32(d2) * SCALE; d3 = rsum32(d3) * SCALE;
        oupd(d0, d1, d2, d3, vv, m0,m1,m2,m3, l0,l1,l2,l3, a0,a1,a2,a3);
    }

    *(float4*)&acc_s[hw][0][4 * ln] = a0;
    *(float4*)&acc_s[hw][1][4 * ln] = a1;
    *(float4*)&acc_s[hw][2][4 * ln] = a2;
    *(float4*)&acc_s[hw][3][4 * ln] = a3;
    if (ln == 0) {
        ml_s[hw][0][0] = m0; ml_s[hw][0][1] = l0;
        ml_s[hw][1][0] = m1; ml_s[hw][1][1] = l1;
        ml_s[hw][2][0] = m2; ml_s[hw][2][1] = l2;
        ml_s[hw][3][0] = m3; ml_s[hw][3][1] = l3;
    }
    __syncthreads();
    for (int o = tid; o < NG * HD; o += 256) {
        const int h = o >> 7, d = o & 127;
        float M = -INFINITY;
        #pragma unroll
        for (int w = 0; w < 8; ++w) M = fmaxf(M, ml_s[w][h][0]);
        float L = 0.f, val = 0.f;
        #pragma unroll
        for (int w = 0; w < 8; ++w) {
            const float mm = ml_s[w][h][0];
            const float sc = (mm == -INFINITY) ? 0.f : __expf(mm - M);
            L += sc * ml_s[w][h][1];
            val += sc * acc_s[w][h][d];
        }
        out[((size_t)(b * NH + kh * NG + h)) * HD + d] = val / L;
    }
}

extern "C" void kernel_launch(void* const* d_in, const int* in_sizes, int n_in,
                              void* d_out, int out_size, void* d_ws, size_t ws_size,
                              hipStream_t stream) {
    const float* q  = (const float*)d_in[0];
    const float* k  = (const float*)d_in[1];
    const float* v  = (const float*)d_in[2];
    const float* kc = (const float*)d_in[3];
    const float* vc = (const float*)d_in[4];
    const int* bt   = (const int*)d_in[5];
    const int* cl   = (const int*)d_in[6];
    const int* sm   = (const int*)d_in[7];
    float* out = (float*)d_out;

    const size_t nidx = (size_t)NB * NKV * NCH * NG;       // 32768 partials
    const size_t need = nidx * (HD + 2) * sizeof(float);   // ~17 MB

    if (ws_size >= need) {
        float* pacc = (float*)d_ws;
        float* pml  = pacc + nidx * HD;
        dim3 gs(NKV, NB, NCH);
        paged_attn_split<<<gs, 128, 0, stream>>>(q, k, v, kc, vc, bt, cl, sm, pacc, pml);
        dim3 gc(NKV, NB);
        paged_attn_combine<<<gc, 256, 0, stream>>>(cl, pacc, pml, out);
    } else {
        dim3 g(NKV, NB);
        paged_attn_mono<<<g, 256, 0, stream>>>(q, k, v, kc, vc, bt, cl, sm, out);
    }
}

// Round 9
// 106.421 us; speedup vs baseline: 4.3426x; 4.3426x over previous
//
#include <hip/hip_runtime.h>

#define NB 64      // batch (sequences)
#define NH 32      // q heads
#define NKV 8      // kv heads
#define HD 128     // head dim
#define NG 4       // q heads per kv head
#define PAGE 32
#define PPS 64     // pages per seq
#define SMAX 2048
#define CHUNK 128  // tokens per split-S block
#define CPP (CHUNK / PAGE)   // 4 pages per chunk
#define NCH (SMAX / CHUNK)   // 16
#define SCALE 0.08838834764831843f

// cross-lane add via DPP (VALU pipe, no LDS). CTRL: 0xB1=quad_perm xor1,
// 0x4E=quad_perm xor2, 0x124=row_ror:4, 0x128=row_ror:8.
template <int CTRL>
__device__ __forceinline__ float dpp_xadd(float v) {
    int t = __builtin_amdgcn_update_dpp(0, __float_as_int(v), CTRL, 0xF, 0xF, false);
    return v + __int_as_float(t);
}

// sum-reduce + broadcast across a 32-lane half-wave: 4 DPP adds + 1 ds_swizzle(xor16)
__device__ __forceinline__ float rsum32(float x) {
    x = dpp_xadd<0xB1>(x);
    x = dpp_xadd<0x4E>(x);
    x = dpp_xadd<0x124>(x);
    x = dpp_xadd<0x128>(x);
    int y = __builtin_amdgcn_ds_swizzle(__float_as_int(x), 0x401F);  // xor 16
    return x + __int_as_float(y);
}

// online-softmax update; defer-rescale (exact: skipping when no new max means e=1)
__device__ __forceinline__ void oupd(
    float d0, float d1, float d2, float d3, const float4 vv,
    float& m0, float& m1, float& m2, float& m3,
    float& l0, float& l1, float& l2, float& l3,
    float4& a0, float4& a1, float4& a2, float4& a3)
{
    if (d0 > m0 || d1 > m1 || d2 > m2 || d3 > m3) {
        const float n0 = fmaxf(m0, d0), n1 = fmaxf(m1, d1);
        const float n2 = fmaxf(m2, d2), n3 = fmaxf(m3, d3);
        const float e0 = __expf(m0 - n0), e1 = __expf(m1 - n1);
        const float e2 = __expf(m2 - n2), e3 = __expf(m3 - n3);
        const float p0 = __expf(d0 - n0), p1 = __expf(d1 - n1);
        const float p2 = __expf(d2 - n2), p3 = __expf(d3 - n3);
        m0 = n0; m1 = n1; m2 = n2; m3 = n3;
        l0 = l0 * e0 + p0; l1 = l1 * e1 + p1;
        l2 = l2 * e2 + p2; l3 = l3 * e3 + p3;
        a0.x = a0.x * e0 + p0 * vv.x; a0.y = a0.y * e0 + p0 * vv.y;
        a0.z = a0.z * e0 + p0 * vv.z; a0.w = a0.w * e0 + p0 * vv.w;
        a1.x = a1.x * e1 + p1 * vv.x; a1.y = a1.y * e1 + p1 * vv.y;
        a1.z = a1.z * e1 + p1 * vv.z; a1.w = a1.w * e1 + p1 * vv.w;
        a2.x = a2.x * e2 + p2 * vv.x; a2.y = a2.y * e2 + p2 * vv.y;
        a2.z = a2.z * e2 + p2 * vv.z; a2.w = a2.w * e2 + p2 * vv.w;
        a3.x = a3.x * e3 + p3 * vv.x; a3.y = a3.y * e3 + p3 * vv.y;
        a3.z = a3.z * e3 + p3 * vv.z; a3.w = a3.w * e3 + p3 * vv.w;
    } else {
        const float p0 = __expf(d0 - m0), p1 = __expf(d1 - m1);
        const float p2 = __expf(d2 - m2), p3 = __expf(d3 - m3);
        l0 += p0; l1 += p1; l2 += p2; l3 += p3;
        a0.x += p0 * vv.x; a0.y += p0 * vv.y; a0.z += p0 * vv.z; a0.w += p0 * vv.w;
        a1.x += p1 * vv.x; a1.y += p1 * vv.y; a1.z += p1 * vv.z; a1.w += p1 * vv.w;
        a2.x += p2 * vv.x; a2.y += p2 * vv.y; a2.z += p2 * vv.z; a2.w += p2 * vv.w;
        a3.x += p3 * vv.x; a3.y += p3 * vv.y; a3.z += p3 * vv.z; a3.w += p3 * vv.w;
    }
}

// ---------------- split-S partial kernel ----------------
// 256 threads (8 half-waves), CHUNK=128 -> 16 tokens per half-wave.
// Grid 8192 blocks: many small equal blocks -> greedy dispatch smooths the
// tail (wall ~ total/chip-rate + one block drain). NO min-waves clause:
// round-8 showed __launch_bounds__(128,8) clamps VGPR to 32 -> 614 MB spills.
__global__ __launch_bounds__(256) void paged_attn_split(
    const float* __restrict__ q,
    const float* __restrict__ knew,
    const float* __restrict__ vnew,
    const float* __restrict__ kcache,
    const float* __restrict__ vcache,
    const int*  __restrict__ btab,
    const int*  __restrict__ ctxlen,
    const int*  __restrict__ slotmap,
    float* __restrict__ pacc,   // [B*NKV*NCH*NG][HD]
    float* __restrict__ pml)    // [B*NKV*NCH*NG][2]
{
    const int kh  = blockIdx.x;
    const int b   = blockIdx.y;
    const int c   = blockIdx.z;
    const int tid = threadIdx.x;   // 0..255

    const int S  = ctxlen[b];
    const int c0 = c * CHUNK;
    if (c0 >= S) return;
    const int send = min(S, c0 + CHUNK);

    __shared__ int   bt_s[CPP];
    __shared__ int   ovr_s[CHUNK];        // -1 or max seq index j (last-write-wins)
    __shared__ float acc_s[8][NG][HD];    // per-half-wave partials (16 KB)
    __shared__ float ml_s[8][NG][2];

    if (tid < CPP) bt_s[tid] = btab[b * PPS + c * CPP + tid];
    if (tid < CHUNK) ovr_s[tid] = -1;
    __syncthreads();
    if (tid < NB) {
        const int slot = slotmap[tid];
        const int pg = slot >> 5, pos = slot & 31;
        #pragma unroll
        for (int i = 0; i < CPP; ++i)
            if (bt_s[i] == pg) atomicMax(&ovr_s[i * PAGE + pos], tid);
    }
    __syncthreads();

    const int hw = tid >> 5;   // half-wave 0..7
    const int ln = tid & 31;   // lane; owns d = 4*ln..4*ln+3

    const float* qb = q + ((size_t)(b * NH + kh * NG)) * HD + 4 * ln;
    const float4 q0 = *(const float4*)(qb + 0 * HD);
    const float4 q1 = *(const float4*)(qb + 1 * HD);
    const float4 q2 = *(const float4*)(qb + 2 * HD);
    const float4 q3 = *(const float4*)(qb + 3 * HD);

    float m0 = -INFINITY, m1 = -INFINITY, m2 = -INFINITY, m3 = -INFINITY;
    float l0 = 0.f, l1 = 0.f, l2 = 0.f, l3 = 0.f;
    float4 a0 = {0,0,0,0}, a1 = {0,0,0,0}, a2 = {0,0,0,0}, a3 = {0,0,0,0};

    auto addr = [&](int sg, const float*& kp, const float*& vp) {
        const int r  = sg - c0;
        const int ov = ovr_s[r];
        if (ov >= 0) {
            const size_t o = ((size_t)ov * NKV + kh) * HD + 4 * ln;
            kp = knew + o; vp = vnew + o;
        } else {
            const size_t o = (((size_t)bt_s[r >> 5] * PAGE + (r & 31)) * NKV + kh) * HD + 4 * ln;
            kp = kcache + o; vp = vcache + o;
        }
    };

    int s = c0 + hw;
    for (; s + 8 < send; s += 16) {          // 2-token unroll: s and s+8
        const float *kpA, *vpA, *kpB, *vpB;
        addr(s,     kpA, vpA);
        addr(s + 8, kpB, vpB);
        const float4 kA = *(const float4*)kpA;
        const float4 kB = *(const float4*)kpB;
        const float4 vA = *(const float4*)vpA;
        const float4 vB = *(const float4*)vpB;

        float dA0 = q0.x*kA.x + q0.y*kA.y + q0.z*kA.z + q0.w*kA.w;
        float dA1 = q1.x*kA.x + q1.y*kA.y + q1.z*kA.z + q1.w*kA.w;
        float dA2 = q2.x*kA.x + q2.y*kA.y + q2.z*kA.z + q2.w*kA.w;
        float dA3 = q3.x*kA.x + q3.y*kA.y + q3.z*kA.z + q3.w*kA.w;
        float dB0 = q0.x*kB.x + q0.y*kB.y + q0.z*kB.z + q0.w*kB.w;
        float dB1 = q1.x*kB.x + q1.y*kB.y + q1.z*kB.z + q1.w*kB.w;
        float dB2 = q2.x*kB.x + q2.y*kB.y + q2.z*kB.z + q2.w*kB.w;
        float dB3 = q3.x*kB.x + q3.y*kB.y + q3.z*kB.z + q3.w*kB.w;

        dA0 = rsum32(dA0) * SCALE; dA1 = rsum32(dA1) * SCALE;
        dA2 = rsum32(dA2) * SCALE; dA3 = rsum32(dA3) * SCALE;
        dB0 = rsum32(dB0) * SCALE; dB1 = rsum32(dB1) * SCALE;
        dB2 = rsum32(dB2) * SCALE; dB3 = rsum32(dB3) * SCALE;

        oupd(dA0, dA1, dA2, dA3, vA, m0,m1,m2,m3, l0,l1,l2,l3, a0,a1,a2,a3);
        oupd(dB0, dB1, dB2, dB3, vB, m0,m1,m2,m3, l0,l1,l2,l3, a0,a1,a2,a3);
    }
    if (s < send) {                           // single-token tail
        const float *kp, *vp;
        addr(s, kp, vp);
        const float4 kv = *(const float4*)kp;
        const float4 vv = *(const float4*)vp;
        float d0 = q0.x*kv.x + q0.y*kv.y + q0.z*kv.z + q0.w*kv.w;
        float d1 = q1.x*kv.x + q1.y*kv.y + q1.z*kv.z + q1.w*kv.w;
        float d2 = q2.x*kv.x + q2.y*kv.y + q2.z*kv.z + q2.w*kv.w;
        float d3 = q3.x*kv.x + q3.y*kv.y + q3.z*kv.z + q3.w*kv.w;
        d0 = rsum32(d0) * SCALE; d1 = rsum32(d1) * SCALE;
        d2 = rsum32(d2) * SCALE; d3 = rsum32(d3) * SCALE;
        oupd(d0, d1, d2, d3, vv, m0,m1,m2,m3, l0,l1,l2,l3, a0,a1,a2,a3);
    }

    *(float4*)&acc_s[hw][0][4 * ln] = a0;
    *(float4*)&acc_s[hw][1][4 * ln] = a1;
    *(float4*)&acc_s[hw][2][4 * ln] = a2;
    *(float4*)&acc_s[hw][3][4 * ln] = a3;
    if (ln == 0) {
        ml_s[hw][0][0] = m0; ml_s[hw][0][1] = l0;
        ml_s[hw][1][0] = m1; ml_s[hw][1][1] = l1;
        ml_s[hw][2][0] = m2; ml_s[hw][2][1] = l2;
        ml_s[hw][3][0] = m3; ml_s[hw][3][1] = l3;
    }
    __syncthreads();

    for (int o = tid; o < NG * HD; o += 256) {
        const int h = o >> 7;
        const int d = o & 127;
        float M = -INFINITY;
        #pragma unroll
        for (int w = 0; w < 8; ++w) M = fmaxf(M, ml_s[w][h][0]);
        float L = 0.f, val = 0.f;
        #pragma unroll
        for (int w = 0; w < 8; ++w) {
            const float mm = ml_s[w][h][0];
            const float sc = (mm == -INFINITY) ? 0.f : __expf(mm - M);
            L   += sc * ml_s[w][h][1];
            val += sc * acc_s[w][h][d];
        }
        const size_t idx = ((size_t)((b * NKV + kh) * NCH + c) * NG + h);
        pacc[idx * HD + d] = val;
        if (d == 0) { pml[idx * 2] = M; pml[idx * 2 + 1] = L; }
    }
}

// ---------------- combine kernel ----------------
__global__ __launch_bounds__(256) void paged_attn_combine(
    const int*  __restrict__ ctxlen,
    const float* __restrict__ pacc,
    const float* __restrict__ pml,
    float* __restrict__ out)
{
    const int kh  = blockIdx.x;
    const int b   = blockIdx.y;
    const int tid = threadIdx.x;
    const int S   = ctxlen[b];
    const int nch = (S + CHUNK - 1) / CHUNK;

    __shared__ float ml_s[NCH][NG][2];
    if (tid < nch * NG) {
        const int cc = tid / NG, h = tid % NG;
        const size_t idx = ((size_t)((b * NKV + kh) * NCH + cc) * NG + h);
        ml_s[cc][h][0] = pml[idx * 2];
        ml_s[cc][h][1] = pml[idx * 2 + 1];
    }
    __syncthreads();

    for (int o = tid; o < NG * HD; o += 256) {
        const int h = o >> 7;
        const int d = o & 127;
        float M = -INFINITY;
        for (int cc = 0; cc < nch; ++cc) M = fmaxf(M, ml_s[cc][h][0]);
        float L = 0.f, val = 0.f;
        for (int cc = 0; cc < nch; ++cc) {
            const float sc = __expf(ml_s[cc][h][0] - M);
            L   += sc * ml_s[cc][h][1];
            val += sc * pacc[((size_t)((b * NKV + kh) * NCH + cc) * NG + h) * HD + d];
        }
        out[((size_t)(b * NH + kh * NG + h)) * HD + d] = val / L;
    }
}

// ---------------- monolithic fallback (only if ws too small) ----------------
__global__ __launch_bounds__(256) void paged_attn_mono(
    const float* __restrict__ q, const float* __restrict__ knew,
    const float* __restrict__ vnew, const float* __restrict__ kcache,
    const float* __restrict__ vcache, const int* __restrict__ btab,
    const int* __restrict__ ctxlen, const int* __restrict__ slotmap,
    float* __restrict__ out)
{
    const int kh  = blockIdx.x;
    const int b   = blockIdx.y;
    const int tid = threadIdx.x;

    __shared__ int   bt_s[PPS];
    __shared__ int   slot_s[NB];
    __shared__ short ovr_s[SMAX];
    __shared__ float acc_s[8][NG][HD];
    __shared__ float ml_s[8][NG][2];

    if (tid < PPS)              bt_s[tid]        = btab[b * PPS + tid];
    if (tid >= 64 && tid < 128) slot_s[tid - 64] = slotmap[tid - 64];
    for (int i = tid; i < SMAX; i += 256) ovr_s[i] = -1;
    __syncthreads();
    if (tid < PPS) {
        const int page = bt_s[tid];
        for (int j = 0; j < NB; ++j) {
            const int slot = slot_s[j];
            if ((slot >> 5) == page) ovr_s[tid * PAGE + (slot & 31)] = (short)j;
        }
    }
    __syncthreads();

    const int S  = ctxlen[b];
    const int hw = tid >> 5;
    const int ln = tid & 31;

    const float* qb = q + ((size_t)(b * NH + kh * NG)) * HD + 4 * ln;
    const float4 q0 = *(const float4*)(qb + 0 * HD);
    const float4 q1 = *(const float4*)(qb + 1 * HD);
    const float4 q2 = *(const float4*)(qb + 2 * HD);
    const float4 q3 = *(const float4*)(qb + 3 * HD);

    float m0 = -INFINITY, m1 = -INFINITY, m2 = -INFINITY, m3 = -INFINITY;
    float l0 = 0.f, l1 = 0.f, l2 = 0.f, l3 = 0.f;
    float4 a0 = {0,0,0,0}, a1 = {0,0,0,0}, a2 = {0,0,0,0}, a3 = {0,0,0,0};

    for (int s = hw; s < S; s += 8) {
        const int ov = ovr_s[s];
        const float* kp; const float* vp;
        if (ov >= 0) {
            const size_t o = ((size_t)ov * NKV + kh) * HD + 4 * ln;
            kp = knew + o; vp = vnew + o;
        } else {
            const size_t o = (((size_t)bt_s[s >> 5] * PAGE + (s & 31)) * NKV + kh) * HD + 4 * ln;
            kp = kcache + o; vp = vcache + o;
        }
        const float4 kv = *(const float4*)kp;
        const float4 vv = *(const float4*)vp;
        float d0 = q0.x*kv.x + q0.y*kv.y + q0.z*kv.z + q0.w*kv.w;
        float d1 = q1.x*kv.x + q1.y*kv.y + q1.z*kv.z + q1.w*kv.w;
        float d2 = q2.x*kv.x + q2.y*kv.y + q2.z*kv.z + q2.w*kv.w;
        float d3 = q3.x*kv.x + q3.y*kv.y + q3.z*kv.z + q3.w*kv.w;
        d0 = rsum32(d0) * SCALE; d1 = rsum32(d1) * SCALE;
        d2 = rsum32(d2) * SCALE; d3 = rsum32(d3) * SCALE;
        oupd(d0, d1, d2, d3, vv, m0,m1,m2,m3, l0,l1,l2,l3, a0,a1,a2,a3);
    }

    *(float4*)&acc_s[hw][0][4 * ln] = a0;
    *(float4*)&acc_s[hw][1][4 * ln] = a1;
    *(float4*)&acc_s[hw][2][4 * ln] = a2;
    *(float4*)&acc_s[hw][3][4 * ln] = a3;
    if (ln == 0) {
        ml_s[hw][0][0] = m0; ml_s[hw][0][1] = l0;
        ml_s[hw][1][0] = m1; ml_s[hw][1][1] = l1;
        ml_s[hw][2][0] = m2; ml_s[hw][2][1] = l2;
        ml_s[hw][3][0] = m3; ml_s[hw][3][1] = l3;
    }
    __syncthreads();
    for (int o = tid; o < NG * HD; o += 256) {
        const int h = o >> 7, d = o & 127;
        float M = -INFINITY;
        #pragma unroll
        for (int w = 0; w < 8; ++w) M = fmaxf(M, ml_s[w][h][0]);
        float L = 0.f, val = 0.f;
        #pragma unroll
        for (int w = 0; w < 8; ++w) {
            const float mm = ml_s[w][h][0];
            const float sc = (mm == -INFINITY) ? 0.f : __expf(mm - M);
            L += sc * ml_s[w][h][1];
            val += sc * acc_s[w][h][d];
        }
        out[((size_t)(b * NH + kh * NG + h)) * HD + d] = val / L;
    }
}

extern "C" void kernel_launch(void* const* d_in, const int* in_sizes, int n_in,
                              void* d_out, int out_size, void* d_ws, size_t ws_size,
                              hipStream_t stream) {
    const float* q  = (const float*)d_in[0];
    const float* k  = (const float*)d_in[1];
    const float* v  = (const float*)d_in[2];
    const float* kc = (const float*)d_in[3];
    const float* vc = (const float*)d_in[4];
    const int* bt   = (const int*)d_in[5];
    const int* cl   = (const int*)d_in[6];
    const int* sm   = (const int*)d_in[7];
    float* out = (float*)d_out;

    const size_t nidx = (size_t)NB * NKV * NCH * NG;       // 32768 partials
    const size_t need = nidx * (HD + 2) * sizeof(float);   // ~17 MB

    if (ws_size >= need) {
        float* pacc = (float*)d_ws;
        float* pml  = pacc + nidx * HD;
        dim3 gs(NKV, NB, NCH);
        paged_attn_split<<<gs, 256, 0, stream>>>(q, k, v, kc, vc, bt, cl, sm, pacc, pml);
        dim3 gc(NKV, NB);
        paged_attn_combine<<<gc, 256, 0, stream>>>(cl, pacc, pml, out);
    } else {
        dim3 g(NKV, NB);
        paged_attn_mono<<<g, 256, 0, stream>>>(q, k, v, kc, vc, bt, cl, sm, out);
    }
}